// Round 1
// 3309.291 us; speedup vs baseline: 2.4014x; 2.4014x over previous
//
#include <hip/hip_runtime.h>
#include <cstdint>
#include <cstddef>

// SimpleRNN on MI355X.
// Outputs (fp32, concatenated): out0 output_tensor (512,64,256), out1 input_proj (64,512,1024),
// out2 tot_rnnhid (64,512,1024), out3 tot_output (64,512,256).
// Pipeline: prep (transpose Win/Wout to bf16 in ws) -> input_proj GEMM (writes out1)
//  -> persistent scan (256 WGs = 1/CU, Wr bf16 in VGPR B-frags, per-step flag sync,
//     y-history bf16 parked in out0/out3 regions) -> output GEMM (reads out2, writes out0/out3).
// R1->R2: cooperative launch silently failed; replaced with plain launch (256 blocks co-resident).
// R2->R3 (this round): scan was pure sync-latency (MfmaUtil 1.5%, HBM 0.6%). Removed the
//  per-step agent fences (buffer_inv/buffer_wbl2 = XCD-wide L2 inv/wb, 32 WGs/XCD each step);
//  all cross-WG traffic is agent-scope atomics (L3 coherence point) so ordering only needs
//  vmcnt(0) drain. hout (out2) stores now PLAIN (read only by next kernel; rides L2).
//  Per-WAVE flags (64/group, 16B apart): each wave publishes its 16-col slice after its own
//  s_waitcnt vmcnt(0) -- no barrier on the release path. Only wave 0 polls (64 lanes, 1 flag
//  each), then an intra-CU barrier releases waves 1-3.

typedef short bf16x8 __attribute__((ext_vector_type(8)));
typedef float f32x4  __attribute__((ext_vector_type(4)));

#define O1_OFF 8388608UL
#define O2_OFF 41943040UL
#define O3_OFF 75497472UL

__device__ __forceinline__ unsigned short f2bf(float f) {
    unsigned u = __float_as_uint(f);
    u += 0x7FFFu + ((u >> 16) & 1u);   // round-to-nearest-even
    return (unsigned short)(u >> 16);
}

// ---------------------------------------------------------------------------
// Prep: Win (256k x 1024n) -> winT bf16 [1024n][256k];  Wout (1024k x 256n) -> woutT bf16 [256n][1024k]
// ---------------------------------------------------------------------------
__global__ void prep_transpose(const float* __restrict__ Win, const float* __restrict__ Wout,
                               unsigned short* __restrict__ winT, unsigned short* __restrict__ woutT)
{
    __shared__ float tbuf[64 * 65];
    const int tid = threadIdx.x;
    const int bx = blockIdx.x;
    const float* src; unsigned short* dst; int k0, n0, srcld, dstld;
    if (bx < 64) { int tk = bx & 3, tn = bx >> 2; k0 = tk * 64; n0 = tn * 64; src = Win;  srcld = 1024; dst = winT;  dstld = 256; }
    else         { int b2 = bx - 64; int tk = b2 >> 2, tn = b2 & 3; k0 = tk * 64; n0 = tn * 64; src = Wout; srcld = 256;  dst = woutT; dstld = 1024; }

    for (int it = 0; it < 16; ++it) {
        int flat = it * 256 + tid;
        int k = flat >> 6, nn = flat & 63;
        tbuf[k * 65 + nn] = src[(size_t)(k0 + k) * srcld + n0 + nn];
    }
    __syncthreads();
    int* d32 = (int*)dst;
    for (int it = 0; it < 8; ++it) {
        int flat = it * 256 + tid;            // 0..2047
        int nn = flat >> 5, kd = flat & 31;   // kd = k-pair index
        float v0 = tbuf[(2 * kd) * 65 + nn];
        float v1 = tbuf[(2 * kd + 1) * 65 + nn];
        d32[(size_t)(n0 + nn) * (dstld / 2) + (k0 / 2) + kd] = (int)(f2bf(v0) | ((unsigned)f2bf(v1) << 16));
    }
}

// ---------------------------------------------------------------------------
// Phase A: input_proj = x(32768r x 256k) @ Win(256k x 1024n), out1[(b*512+t)*1024+n], r = t*64+b
// Grid 256 WGs: bx&3 = n-slice (256 cols), bx>>2 = wg-m (each does 16 m-tiles of 32 rows)
// ---------------------------------------------------------------------------
__launch_bounds__(256, 1)
__global__ void input_proj_kernel(const float* __restrict__ x, const unsigned short* __restrict__ winT,
                                  float* __restrict__ ip)
{
    extern __shared__ short lds[];
    short* win_s = lds;             // [256 n][264] bf16
    short* x_s   = lds + 256 * 264; // [32 m][264] bf16
    const int tid = threadIdx.x;
    const int lane = tid & 63, wv = tid >> 6;
    const int nslice = blockIdx.x & 3;
    const int wgm = blockIdx.x >> 2;
    const int n0 = nslice * 256;
    const int n = lane & 15, q = lane >> 4;

    { // stage WinT slice, coalesced + conflict-free
        const int* src = (const int*)winT;   // [1024][128 dwords]
        int* dstl = (int*)win_s;             // pitch 132 dwords
        for (int it = 0; it < 128; ++it) {
            int flat = it * 256 + tid;
            int nn = flat >> 7, kd = flat & 127;
            dstl[nn * 132 + kd] = src[(size_t)(n0 + nn) * 128 + kd];
        }
    }
    __syncthreads();

    const int msub = (wv & 1) * 16;
    const int ntbase = (wv >> 1) * 8;

    for (int i = 0; i < 16; ++i) {
        int mt = wgm * 16 + i;
        int r0 = mt * 32;
        { // stage x tile 32x256 fp32 -> bf16
            for (int it = 0; it < 16; ++it) {
                int flat = it * 256 + tid;     // 0..4095
                int rr = flat >> 7, kp = flat & 127;
                const float* xp = x + (size_t)(r0 + rr) * 256 + kp * 2;
                ((int*)x_s)[rr * 132 + kp] = (int)(f2bf(xp[0]) | ((unsigned)f2bf(xp[1]) << 16));
            }
        }
        __syncthreads();

        f32x4 acc[8] = {};
#pragma unroll
        for (int kc = 0; kc < 8; ++kc) {
            bf16x8 af = *(const bf16x8*)(x_s + (msub + n) * 264 + kc * 32 + q * 8);
#pragma unroll
            for (int u = 0; u < 8; ++u) {
                bf16x8 bfv = *(const bf16x8*)(win_s + ((ntbase + u) * 16 + n) * 264 + kc * 32 + q * 8);
                acc[u] = __builtin_amdgcn_mfma_f32_16x16x32_bf16(af, bfv, acc[u], 0, 0, 0);
            }
        }
#pragma unroll
        for (int u = 0; u < 8; ++u) {
            int ncol = n0 + (ntbase + u) * 16 + n;
#pragma unroll
            for (int rr = 0; rr < 4; ++rr) {
                int R = r0 + msub + q * 4 + rr;
                int t = R >> 6, b = R & 63;
                ip[((size_t)b * 512 + t) * 1024 + ncol] = acc[u][rr];
            }
        }
        __syncthreads();
    }
}

// ---------------------------------------------------------------------------
// Persistent scan. 256 WGs x 256 thr (plain launch; 1 WG/CU => all co-resident).
// group g = 4 batches, 16 WGs/group x 64 cols. Wave = 16 cols; Wr bf16 B-frags in VGPRs.
// Per step: wave0 polls 64 per-wave flags -> barrier -> stage y_{t-1} (bf16, agent-atomic
// loads) to LDS -> barrier -> 32 MFMA -> h update -> store h fp32 plain (out2) + tanh(h)
// bf16 atomic (y-history in out0/out3) -> per-wave vmcnt(0) drain -> per-wave flag.
// NO agent fences: all cross-WG data moves via agent-scope atomics (L3 coherence point);
// each producer's 64-col slice is exactly one 128B line per row, first-touched by
// consumers only after its flag => no stale-line window even if atomics are L2-cached.
// ---------------------------------------------------------------------------
__launch_bounds__(256, 1)
__global__ void rnn_scan(const float* __restrict__ Wr, const float* __restrict__ bias,
                         const float* __restrict__ ip, float* __restrict__ hout,
                         char* ybase0, char* ybase3, int* flags)
{
    __shared__ short y_lds[4 * 1032];
    const int tid = threadIdx.x;
    const int lane = tid & 63;
    const int wv = tid >> 6;
    const int bx = blockIdx.x;
    const int xcd = bx & 7;
    const int j = bx >> 3;              // 0..31
    const int g = xcd + 8 * (j & 1);    // group 0..15
    const int w = j >> 1;               // slice 0..15
    const int b0 = g * 4;
    const int colbase = w * 64 + wv * 16;
    const int n = lane & 15;            // col within tile; also A-frag row index
    const int q = lane >> 4;
    const int col = colbase + n;

    // Load Wr B-frags: lane holds Wr[kc*32+q*8+jj][col], bf16
    bf16x8 wrf[32];
#pragma unroll
    for (int kc = 0; kc < 32; ++kc) {
        int kbase = kc * 32 + q * 8;
        union { bf16x8 v; unsigned short u[8]; } tmp;
#pragma unroll
        for (int jj = 0; jj < 8; ++jj)
            tmp.u[jj] = f2bf(Wr[(size_t)(kbase + jj) * 1024 + col]);
        wrf[kc] = tmp.v;
    }
    const float biasv = bias[col];
    float h[4] = {0.f, 0.f, 0.f, 0.f};
    // per-wave flags: index (g*64 + w*4 + wv), spaced 16B. 16 groups * 64 * 16B = 16KB.
    int* wflag = flags + ((g * 64 + w * 4 + wv) << 2);
    int* pflag = flags + ((g * 64 + lane) << 2);   // wave0: lane -> (w=lane>>2, wv=lane&3)

    for (int t = 0; t < 512; ++t) {
        // prefetch ip for this step (lanes 0-15 hold batches 0-3 in regs, C-frag layout)
        float ipv[4] = {0.f, 0.f, 0.f, 0.f};
        if (lane < 16) {
#pragma unroll
            for (int rr = 0; rr < 4; ++rr)
                ipv[rr] = ip[((size_t)(b0 + rr) * 512 + t) * 1024 + col];
        }

        f32x4 acc0 = {0.f, 0.f, 0.f, 0.f}, acc1 = {0.f, 0.f, 0.f, 0.f};
        if (t > 0) {
            // wave 0 waits for all 64 per-wave producers of y_{t-1};
            // watchdog converts deadlock -> wrong answer
            if (wv == 0) {
                int spins = 0;
                while (true) {
                    int v = __hip_atomic_load(pflag, __ATOMIC_RELAXED, __HIP_MEMORY_SCOPE_AGENT);
                    if (__all(v >= t)) break;
                    if (__builtin_expect(++spins > (1 << 22), 0)) break;
                    __builtin_amdgcn_s_sleep(1);
                }
            }
            asm volatile("" ::: "memory");
            __syncthreads();   // releases waves 1-3; also fences y_lds reuse across steps

            // stage y_{t-1} rows b0..b0+3 (4 x 1024 bf16 = 2048 dwords) into LDS
            const int* ysrc = (const int*)((t - 1) < 256 ? (ybase0 + (size_t)(t - 1) * 131072)
                                                         : (ybase3 + (size_t)(t - 1 - 256) * 131072));
            {
                int r = tid >> 6;       // 0..3
                int c0 = tid & 63;
#pragma unroll
                for (int it = 0; it < 8; ++it) {
                    int c = c0 + it * 64;
                    int v = __hip_atomic_load(ysrc + (b0 + r) * 512 + c, __ATOMIC_RELAXED, __HIP_MEMORY_SCOPE_AGENT);
                    ((int*)y_lds)[r * 516 + c] = v;
                }
            }
            __syncthreads();

            // MFMA over K=1024: A rows 0-3 = y batches, rows 4-15 zero
#pragma unroll
            for (int kc = 0; kc < 32; kc += 2) {
                bf16x8 a0, a1;
                if (n < 4) {
                    a0 = *(const bf16x8*)(y_lds + n * 1032 + kc * 32 + q * 8);
                    a1 = *(const bf16x8*)(y_lds + n * 1032 + (kc + 1) * 32 + q * 8);
                } else { a0 = (bf16x8)0; a1 = (bf16x8)0; }
                acc0 = __builtin_amdgcn_mfma_f32_16x16x32_bf16(a0, wrf[kc],     acc0, 0, 0, 0);
                acc1 = __builtin_amdgcn_mfma_f32_16x16x32_bf16(a1, wrf[kc + 1], acc1, 0, 0, 0);
            }
        }

        // h update (lanes>=16 compute phantom rows; never stored, A-rows forced zero so harmless)
#pragma unroll
        for (int rr = 0; rr < 4; ++rr) {
            float rv = acc0[rr] + acc1[rr];
            h[rr] = 0.95f * h[rr] + 0.05f * (rv + ipv[rr] + biasv);
        }

        // store h (out2, PLAIN -> local L2, flushed at kernel end) and y=tanh(h) bf16 (history, atomic -> L3)
        if (lane < 16) {
            char* ydst = (t < 256) ? (ybase0 + (size_t)t * 131072) : (ybase3 + (size_t)(t - 256) * 131072);
#pragma unroll
            for (int rr = 0; rr < 4; ++rr) {
                float hv = h[rr];
                hout[((size_t)(b0 + rr) * 512 + t) * 1024 + col] = hv;
                unsigned short yb = f2bf(tanhf(hv));
                __hip_atomic_store((unsigned short*)ydst + (b0 + rr) * 1024 + col, yb,
                                   __ATOMIC_RELAXED, __HIP_MEMORY_SCOPE_AGENT);
            }
        }
        // per-wave release: wait for THIS wave's stores (y atomics complete at L3), then flag.
        asm volatile("s_waitcnt vmcnt(0)" ::: "memory");
        if (lane == 0)
            __hip_atomic_store(wflag, t + 1, __ATOMIC_RELAXED, __HIP_MEMORY_SCOPE_AGENT);
    }
}

// ---------------------------------------------------------------------------
// Phase C: rnn_out = tanh(out2) (32768r x 1024k) @ Wout -> out3[R*256+n] and out0[(t*64+b)*256+n]
// Grid 512 WGs: WG = 64 rows (wave = 16), N=256 full, K in 8 blocks of 128 (WoutT staged in LDS)
// ---------------------------------------------------------------------------
__launch_bounds__(256, 1)
__global__ void out_proj_kernel(const float* __restrict__ h, const unsigned short* __restrict__ woutT,
                                float* __restrict__ out0, float* __restrict__ out3)
{
    extern __shared__ short lds[];      // [256 n][136] bf16 per k-block
    const int tid = threadIdx.x;
    const int lane = tid & 63, wv = tid >> 6;
    const int R0 = blockIdx.x * 64;
    const int n = lane & 15, q = lane >> 4;
    f32x4 acc[16] = {};

    for (int kb = 0; kb < 8; ++kb) {
        { // stage WoutT block, coalesced + conflict-free
            const int* src = (const int*)woutT;   // [256][512 dwords]
            int* dstl = (int*)lds;                // pitch 68 dwords
#pragma unroll
            for (int it = 0; it < 64; ++it) {
                int flat = it * 256 + tid;
                int nn = flat >> 6, kd = flat & 63;
                dstl[nn * 68 + kd] = src[(size_t)nn * 512 + kb * 64 + kd];
            }
        }
        __syncthreads();

        const int row = R0 + wv * 16 + n;
#pragma unroll
        for (int kc = 0; kc < 4; ++kc) {
            int k = kb * 128 + kc * 32 + q * 8;
            const float* hp = h + (size_t)row * 1024 + k;
            union { bf16x8 v; unsigned short u[8]; } af;
#pragma unroll
            for (int jj = 0; jj < 8; ++jj) af.u[jj] = f2bf(tanhf(hp[jj]));
#pragma unroll
            for (int u2 = 0; u2 < 16; ++u2) {
                bf16x8 bfv = *(const bf16x8*)(lds + (u2 * 16 + n) * 136 + kc * 32 + q * 8);
                acc[u2] = __builtin_amdgcn_mfma_f32_16x16x32_bf16(af.v, bfv, acc[u2], 0, 0, 0);
            }
        }
        __syncthreads();
    }
#pragma unroll
    for (int u2 = 0; u2 < 16; ++u2) {
        int ncol = u2 * 16 + n;
#pragma unroll
        for (int rr = 0; rr < 4; ++rr) {
            int R = R0 + wv * 16 + q * 4 + rr;
            int b = R >> 9, t = R & 511;
            float v = acc[u2][rr];
            out3[(size_t)R * 256 + ncol] = v;
            out0[((size_t)t * 64 + b) * 256 + ncol] = v;
        }
    }
}

// ---------------------------------------------------------------------------
extern "C" void kernel_launch(void* const* d_in, const int* in_sizes, int n_in,
                              void* d_out, int out_size, void* d_ws, size_t ws_size,
                              hipStream_t stream)
{
    const float* x    = (const float*)d_in[0];
    const float* Win  = (const float*)d_in[1];
    const float* Wr   = (const float*)d_in[2];
    const float* bias = (const float*)d_in[3];
    const float* Wout = (const float*)d_in[4];
    float* out = (float*)d_out;
    float* o0 = out;
    float* o1 = out + O1_OFF;
    float* o2 = out + O2_OFF;
    float* o3 = out + O3_OFF;

    // ws layout: [0,16K) per-wave flags (poison 0xAA.. reads as negative => safe),
    // [16K,+512K) winT, then woutT
    int* flags = (int*)d_ws;
    unsigned short* winT  = (unsigned short*)((char*)d_ws + 16384);
    unsigned short* woutT = (unsigned short*)((char*)d_ws + 16384 + 524288);

    hipFuncSetAttribute((const void*)input_proj_kernel, hipFuncAttributeMaxDynamicSharedMemorySize, 152064);
    hipFuncSetAttribute((const void*)out_proj_kernel,   hipFuncAttributeMaxDynamicSharedMemorySize, 69632);

    hipLaunchKernelGGL(prep_transpose, dim3(128), dim3(256), 0, stream, Win, Wout, winT, woutT);
    hipLaunchKernelGGL(input_proj_kernel, dim3(256), dim3(256), 152064, stream, x, winT, o1);

    hipLaunchKernelGGL(rnn_scan, dim3(256), dim3(256), 0, stream,
                       Wr, bias, o1, o2, (char*)o0, (char*)o3, flags);

    hipLaunchKernelGGL(out_proj_kernel, dim3(512), dim3(256), 69632, stream, o2, woutT, o0, o3);
}